// Round 9
// baseline (511.758 us; speedup 1.0000x reference)
//
#include <hip/hip_runtime.h>

// Shapes: S=128, I=J=512, CM=256, C=D=32, CZ=128. Output [1,512,512,128] fp32.
#define EPS 1e-5f

typedef _Float16 half8 __attribute__((ext_vector_type(8)));
typedef _Float16 half4 __attribute__((ext_vector_type(4)));
typedef float f32x4 __attribute__((ext_vector_type(4)));

// a/b workspace layout: [2 k-chunks][16384 (i*32+c) rows][72 halves]; cols 0..63 = s_loc, 64..71 pad.
#define AB_STRIDE 72
#define AB_CHUNK  (16384 * AB_STRIDE)

__device__ __forceinline__ void load16_to_lds(const void* g, void* l) {
    __builtin_amdgcn_global_load_lds((__attribute__((address_space(1))) void*)g,
                                     (__attribute__((address_space(3))) void*)l, 16, 0, 0);
}

// ---------------- cvt kernel: WoH (fp16, K permuted to k'=d*32+c) + WabH (fp16) ----------------
__global__ __launch_bounds__(256)
void k_cvt(const float* __restrict__ Wo, const float* __restrict__ Wa,
           const float* __restrict__ Wb, _Float16* __restrict__ WoH,
           _Float16* __restrict__ WabH)
{
    __shared__ _Float16 tile[32 * 36];          // [d][c], pad 36 keeps half4 reads 8B-aligned
    const int t = threadIdx.x;
    if (blockIdx.x < 128) {
        const int n = blockIdx.x;
        float4 v = *(const float4*)(Wo + (size_t)n * 1024 + t * 4);
        int c  = t >> 3;
        int d0 = (t * 4) & 31;
        tile[(d0 + 0) * 36 + c] = (_Float16)v.x;
        tile[(d0 + 1) * 36 + c] = (_Float16)v.y;
        tile[(d0 + 2) * 36 + c] = (_Float16)v.z;
        tile[(d0 + 3) * 36 + c] = (_Float16)v.w;
        __syncthreads();
        int d  = t >> 3;
        int c0 = (t * 4) & 31;
        half4 o = *(const half4*)(tile + d * 36 + c0);
        *(half4*)(WoH + (size_t)n * 1024 + t * 4) = o;
    } else {
        int idx = ((blockIdx.x - 128) * 256 + t) * 4;
        const float* src = (idx < 8192) ? (Wa + idx) : (Wb + (idx - 8192));
        float4 v = *(const float4*)src;
        half4 h;
        h[0] = (_Float16)v.x; h[1] = (_Float16)v.y; h[2] = (_Float16)v.z; h[3] = (_Float16)v.w;
        *(half4*)(WabH + idx) = h;
    }
}

// ---------------- Kernel 1: LN + A/B projection, DMA-pipelined x staging ----------------
// (unchanged from R5/R6 — measured neutral vs scalar variants; k1 is not the bottleneck)
__global__ __launch_bounds__(512, 4)
void k1_ln_proj(const float* __restrict__ x, const float* __restrict__ nw,
                const float* __restrict__ nb, const _Float16* __restrict__ WabH,
                _Float16* __restrict__ aT, _Float16* __restrict__ bT)
{
    __shared__ float    xraw[3 * 8 * 256];   // 24576 B
    __shared__ _Float16 xln[64 * 264];       // 33792 B
    __shared__ _Float16 oT[256 * 40];        // 20480 B

    const int tid  = threadIdx.x;
    const int lane = tid & 63;
    const int w    = tid >> 6;
    const int quad = lane >> 4;
    const int l15  = lane & 15;
    const int i0   = (blockIdx.x >> 2) * 4;
    const int sc   = blockIdx.x & 3;

    const int mt  = w & 3;
    const int ntg = w >> 2;

    const float4 gw = ((const float4*)nw)[lane];
    const float4 gb = ((const float4*)nb)[lane];

    auto src_of = [&](int c) -> const float* {
        int rl = ((c & 7) << 3) + w;
        int s_ = sc * 32 + ((c >> 3) << 4) + (rl >> 2);
        int i_ = i0 + (rl & 3);
        return x + ((size_t)s_ * 512 + i_) * 256;
    };

    load16_to_lds(src_of(0) + lane * 4, xraw + (0 * 8 + w) * 256 + lane * 4);
    load16_to_lds(src_of(1) + lane * 4, xraw + (1 * 8 + w) * 256 + lane * 4);

    int rb = 0;
    for (int half = 0; half < 2; ++half) {
        for (int cc = 0; cc < 8; ++cc) {
            const int c = half * 8 + cc;
            if (c == 15) asm volatile("s_waitcnt vmcnt(0)" ::: "memory");
            else         asm volatile("s_waitcnt vmcnt(1)" ::: "memory");

            const float4 v = *(const float4*)(xraw + (rb * 8 + w) * 256 + lane * 4);
            float sum = v.x + v.y + v.z + v.w;
            float ss  = v.x * v.x + v.y * v.y + v.z * v.z + v.w * v.w;
            #pragma unroll
            for (int off = 32; off > 0; off >>= 1) {
                sum += __shfl_xor(sum, off);
                ss  += __shfl_xor(ss, off);
            }
            float mu  = sum * (1.f / 256.f);
            float var = ss * (1.f / 256.f) - mu * mu;
            float rs  = rsqrtf(var + EPS);
            half4 o;
            o[0] = (_Float16)((v.x - mu) * rs * gw.x + gb.x);
            o[1] = (_Float16)((v.y - mu) * rs * gw.y + gb.y);
            o[2] = (_Float16)((v.z - mu) * rs * gw.z + gb.z);
            o[3] = (_Float16)((v.w - mu) * rs * gw.w + gb.w);
            int rl = (cc << 3) + w;
            *(half4*)(xln + rl * 264 + lane * 4) = o;

            if (c + 2 < 16) {
                int nb3 = rb + 2; if (nb3 >= 3) nb3 -= 3;
                load16_to_lds(src_of(c + 2) + lane * 4, xraw + (nb3 * 8 + w) * 256 + lane * 4);
            }
            ++rb; if (rb == 3) rb = 0;
        }
        asm volatile("s_waitcnt lgkmcnt(0)" ::: "memory");
        __builtin_amdgcn_s_barrier();

        f32x4 acc2[2] = {};
        #pragma unroll
        for (int kk = 0; kk < 8; ++kk) {
            half8 af = *(const half8*)(xln + (mt * 16 + l15) * 264 + kk * 32 + quad * 8);
            #pragma unroll
            for (int t = 0; t < 2; ++t) {
                half8 bf = *(const half8*)(WabH + (ntg * 32 + t * 16 + l15) * 256 + kk * 32 + quad * 8);
                acc2[t] = __builtin_amdgcn_mfma_f32_16x16x32_f16(af, bf, acc2[t], 0, 0, 0);
            }
        }

        #pragma unroll
        for (int t = 0; t < 2; ++t) {
            int c64  = ntg * 32 + t * 16 + l15;
            int base = ((c64 >= 32) ? 128 : 0) + (c64 & 31);
            int s_l  = half * 16 + mt * 4 + quad;
            #pragma unroll
            for (int r = 0; r < 4; ++r)
                oT[(base + r * 32) * 40 + s_l] = (_Float16)acc2[t][r];
        }
        asm volatile("s_waitcnt lgkmcnt(0)" ::: "memory");
        __builtin_amdgcn_s_barrier();
    }

    #pragma unroll
    for (int it2 = 0; it2 < 2; ++it2) {
        int u   = it2 * 512 + tid;
        int row = u >> 2;
        int off = (u & 3) * 8;
        half8 v = *(const half8*)(oT + row * 40 + off);
        _Float16* dst = (row < 128) ? aT : bT;
        int grow = i0 * 32 + (row & 127);
        *(half8*)(dst + (size_t)(sc >> 1) * AB_CHUNK + (size_t)grow * 72 + (sc & 1) * 32 + off) = v;
    }
}

// ---------------- Kernel 2: fused outer-product-mean + Wo projection ----------------
// R7: tile doubled to 8 i x 8 j (64 pairs), 1024 threads (16 waves), grid (64,64).
// Per-wave inner loops identical to the proven 512-thread version (P1 acc[4][4]; P2
// 2 LDS + 1 global stream per kk -- R2 constraint). Halves staging bytes, WoH L2
// traffic, LDS traffic and barriers per output; MFMA unchanged. Occupancy stays
// 16 waves/CU (1 block/CU, 129 KiB LDS < 160 KiB cap).
__global__ __launch_bounds__(1024, 4)
void k2_main(const _Float16* __restrict__ aT, const _Float16* __restrict__ bT,
             const _Float16* __restrict__ WoH, const float* __restrict__ bo,
             float* __restrict__ out)
{
    __shared__ _Float16 smem[66048];               // 132096 B = oL 64 x 1032
    _Float16* sA = smem;                           // 256 rows x 72 (overlaid by oL later)
    _Float16* sB = smem + 256 * AB_STRIDE;         // 256 rows x 72
    _Float16* oL = smem;                           // 64 pairs x 1032

    const int tid  = threadIdx.x;
    const int lane = tid & 63;
    const int w    = tid >> 6;                     // 0..15
    const int quad = lane >> 4;
    const int l15  = lane & 15;
    const int wy   = w >> 2, wx = w & 3;           // 4x4 wave grid for P1

    const int jt = blockIdx.x, it = blockIdx.y;    // 64 x 64
    const char* gA = (const char*)(aT + (size_t)it * 256 * AB_STRIDE);
    const char* gB = (const char*)(bT + (size_t)jt * 256 * AB_STRIDE);

    f32x4 acc[4][4] = {};

    for (int ck = 0; ck < 2; ++ck) {
        // stage: sA 36 segs + sB 36 segs of 1024 B, over 16 waves
        const char* cA = gA + (size_t)ck * (AB_CHUNK * 2);
        const char* cB = gB + (size_t)ck * (AB_CHUNK * 2);
        for (int seg = w; seg < 72; seg += 16) {
            if (seg < 36) load16_to_lds(cA + seg * 1024 + lane * 16, (char*)sA + seg * 1024 + lane * 16);
            else          load16_to_lds(cB + (seg - 36) * 1024 + lane * 16, (char*)sB + (seg - 36) * 1024 + lane * 16);
        }
        __syncthreads();

        #pragma unroll
        for (int kloc = 0; kloc < 2; ++kloc) {
            half8 af[4], bf[4];
            #pragma unroll
            for (int mt = 0; mt < 4; ++mt)
                af[mt] = *(const half8*)(sA + (wy * 64 + mt * 16 + l15) * AB_STRIDE + kloc * 32 + quad * 8);
            #pragma unroll
            for (int nt = 0; nt < 4; ++nt)
                bf[nt] = *(const half8*)(sB + (wx * 64 + nt * 16 + l15) * AB_STRIDE + kloc * 32 + quad * 8);
            #pragma unroll
            for (int mt = 0; mt < 4; ++mt)
                #pragma unroll
                for (int nt = 0; nt < 4; ++nt)
                    acc[mt][nt] = __builtin_amdgcn_mfma_f32_16x16x32_f16(af[mt], bf[nt], acc[mt][nt], 0, 0, 0);
        }
        __syncthreads();
    }

    // C/D -> A-operand transform into oL[pair][k'=d*32+c], XOR-swizzled 16B chunks.
    // m = wy*64+mt*16+quad*4+r: il = wy*2+(mt>>1), c = (mt&1)*16+quad*4+r
    // n = wx*64+nt*16+l15:      jl = wx*2+(nt>>1), d = (nt&1)*16+l15
    // pair = il*8 + jl  (8 j per i now)
    #pragma unroll
    for (int mt = 0; mt < 4; ++mt) {
        int c0     = (mt & 1) * 16 + quad * 4;
        int chunk3 = (c0 >> 3);
        int il     = wy * 2 + (mt >> 1);
        #pragma unroll
        for (int nt = 0; nt < 4; ++nt) {
            int d    = (nt & 1) * 16 + l15;
            int jl   = wx * 2 + (nt >> 1);
            int pair = il * 8 + jl;
            int cS   = (c0 & 7) + ((chunk3 ^ ((d >> 1) & 3)) << 3);   // swizzled c
            half4 v;
            v[0] = (_Float16)(acc[mt][nt][0] * (1.f / 128.f));
            v[1] = (_Float16)(acc[mt][nt][1] * (1.f / 128.f));
            v[2] = (_Float16)(acc[mt][nt][2] * (1.f / 128.f));
            v[3] = (_Float16)(acc[mt][nt][3] * (1.f / 128.f));
            *(half4*)(oL + pair * 1032 + d * 32 + cS) = v;
        }
    }
    __syncthreads();

    // Phase 2: wave w -> mh = w>>3 (32-pair M half), n-tile = w&7 (16 cz cols), K = 1024.
    // Waves w and w+8 share WoH rows (L1-friendly). 2 LDS + 1 global per kk.
    f32x4 zacc[2] = {};
    const int mh = w >> 3;
    const int n0 = (w & 7) * 16 + l15;
    const int arow = (mh * 32 + l15) * 1032;
    #pragma unroll 4
    for (int kk = 0; kk < 32; ++kk) {
        int csw = (quad ^ ((kk >> 1) & 3)) * 8;    // un-swizzle chunk
        half8 oa0 = *(const half8*)(oL + arow + kk * 32 + csw);
        half8 oa1 = *(const half8*)(oL + arow + 16 * 1032 + kk * 32 + csw);
        half8 w0  = *(const half8*)(WoH + (size_t)n0 * 1024 + kk * 32 + quad * 8);
        zacc[0] = __builtin_amdgcn_mfma_f32_16x16x32_f16(oa0, w0, zacc[0], 0, 0, 0);
        zacc[1] = __builtin_amdgcn_mfma_f32_16x16x32_f16(oa1, w0, zacc[1], 0, 0, 0);
    }

    // epilogue: pair = mh*32 + mt2*16 + quad*4 + r -> il = pair>>3, jl = pair&7
    float bias = bo[n0];
    #pragma unroll
    for (int mt2 = 0; mt2 < 2; ++mt2) {
        #pragma unroll
        for (int r = 0; r < 4; ++r) {
            int pair = mh * 32 + mt2 * 16 + quad * 4 + r;
            int il = pair >> 3;
            int jl = pair & 7;
            out[(((size_t)(it * 8 + il)) * 512 + jt * 8 + jl) * 128 + n0] = zacc[mt2][r] + bias;
        }
    }
}

extern "C" void kernel_launch(void* const* d_in, const int* in_sizes, int n_in,
                              void* d_out, int out_size, void* d_ws, size_t ws_size,
                              hipStream_t stream)
{
    const float* x      = (const float*)d_in[0];
    const float* norm_w = (const float*)d_in[1];
    const float* norm_b = (const float*)d_in[2];
    const float* Wa     = (const float*)d_in[3];
    const float* Wb     = (const float*)d_in[4];
    const float* Wo     = (const float*)d_in[5];
    const float* bo     = (const float*)d_in[6];
    float* out = (float*)d_out;

    _Float16* aT   = (_Float16*)d_ws;                      // 2*16384*72
    _Float16* bT   = aT + 2 * (size_t)AB_CHUNK;
    _Float16* WoH  = bT + 2 * (size_t)AB_CHUNK;            // 131072
    _Float16* WabH = WoH + 131072;                         // 16384

    k_cvt<<<144, 256, 0, stream>>>(Wo, Wa, Wb, WoH, WabH);
    k1_ln_proj<<<512, 512, 0, stream>>>(x, norm_w, norm_b, WabH, aT, bT);
    k2_main<<<dim3(64, 64), 1024, 0, stream>>>(aT, bT, WoH, bo, out);
}

// Round 10
// 477.410 us; speedup vs baseline: 1.0719x; 1.0719x over previous
//
#include <hip/hip_runtime.h>

// Shapes: S=128, I=J=512, CM=256, C=D=32, CZ=128. Output [1,512,512,128] fp32.
#define EPS 1e-5f

typedef _Float16 half8 __attribute__((ext_vector_type(8)));
typedef _Float16 half4 __attribute__((ext_vector_type(4)));
typedef float f32x4 __attribute__((ext_vector_type(4)));
typedef float f32x16 __attribute__((ext_vector_type(16)));

// a/b workspace layout: [2 k-chunks][16384 (i*32+c) rows][72 halves]; cols 0..63 = s_loc, 64..71 pad.
#define AB_STRIDE 72
#define AB_CHUNK  (16384 * AB_STRIDE)

__device__ __forceinline__ void load16_to_lds(const void* g, void* l) {
    __builtin_amdgcn_global_load_lds((__attribute__((address_space(1))) void*)g,
                                     (__attribute__((address_space(3))) void*)l, 16, 0, 0);
}

// ---------------- cvt kernel: WoH (fp16, K permuted to k'=d*32+c) + WabH (fp16) ----------------
__global__ __launch_bounds__(256)
void k_cvt(const float* __restrict__ Wo, const float* __restrict__ Wa,
           const float* __restrict__ Wb, _Float16* __restrict__ WoH,
           _Float16* __restrict__ WabH)
{
    __shared__ _Float16 tile[32 * 36];          // [d][c], pad 36 keeps half4 reads 8B-aligned
    const int t = threadIdx.x;
    if (blockIdx.x < 128) {
        const int n = blockIdx.x;
        float4 v = *(const float4*)(Wo + (size_t)n * 1024 + t * 4);
        int c  = t >> 3;
        int d0 = (t * 4) & 31;
        tile[(d0 + 0) * 36 + c] = (_Float16)v.x;
        tile[(d0 + 1) * 36 + c] = (_Float16)v.y;
        tile[(d0 + 2) * 36 + c] = (_Float16)v.z;
        tile[(d0 + 3) * 36 + c] = (_Float16)v.w;
        __syncthreads();
        int d  = t >> 3;
        int c0 = (t * 4) & 31;
        half4 o = *(const half4*)(tile + d * 36 + c0);
        *(half4*)(WoH + (size_t)n * 1024 + t * 4) = o;
    } else {
        int idx = ((blockIdx.x - 128) * 256 + t) * 4;
        const float* src = (idx < 8192) ? (Wa + idx) : (Wb + (idx - 8192));
        float4 v = *(const float4*)src;
        half4 h;
        h[0] = (_Float16)v.x; h[1] = (_Float16)v.y; h[2] = (_Float16)v.z; h[3] = (_Float16)v.w;
        *(half4*)(WabH + idx) = h;
    }
}

// ---------------- Kernel 1: LN + A/B projection, DMA-pipelined x staging ----------------
// (unchanged — measured neutral vs scalar variants; k1 is not the bottleneck)
__global__ __launch_bounds__(512, 4)
void k1_ln_proj(const float* __restrict__ x, const float* __restrict__ nw,
                const float* __restrict__ nb, const _Float16* __restrict__ WabH,
                _Float16* __restrict__ aT, _Float16* __restrict__ bT)
{
    __shared__ float    xraw[3 * 8 * 256];   // 24576 B
    __shared__ _Float16 xln[64 * 264];       // 33792 B
    __shared__ _Float16 oT[256 * 40];        // 20480 B

    const int tid  = threadIdx.x;
    const int lane = tid & 63;
    const int w    = tid >> 6;
    const int quad = lane >> 4;
    const int l15  = lane & 15;
    const int i0   = (blockIdx.x >> 2) * 4;
    const int sc   = blockIdx.x & 3;

    const int mt  = w & 3;
    const int ntg = w >> 2;

    const float4 gw = ((const float4*)nw)[lane];
    const float4 gb = ((const float4*)nb)[lane];

    auto src_of = [&](int c) -> const float* {
        int rl = ((c & 7) << 3) + w;
        int s_ = sc * 32 + ((c >> 3) << 4) + (rl >> 2);
        int i_ = i0 + (rl & 3);
        return x + ((size_t)s_ * 512 + i_) * 256;
    };

    load16_to_lds(src_of(0) + lane * 4, xraw + (0 * 8 + w) * 256 + lane * 4);
    load16_to_lds(src_of(1) + lane * 4, xraw + (1 * 8 + w) * 256 + lane * 4);

    int rb = 0;
    for (int half = 0; half < 2; ++half) {
        for (int cc = 0; cc < 8; ++cc) {
            const int c = half * 8 + cc;
            if (c == 15) asm volatile("s_waitcnt vmcnt(0)" ::: "memory");
            else         asm volatile("s_waitcnt vmcnt(1)" ::: "memory");

            const float4 v = *(const float4*)(xraw + (rb * 8 + w) * 256 + lane * 4);
            float sum = v.x + v.y + v.z + v.w;
            float ss  = v.x * v.x + v.y * v.y + v.z * v.z + v.w * v.w;
            #pragma unroll
            for (int off = 32; off > 0; off >>= 1) {
                sum += __shfl_xor(sum, off);
                ss  += __shfl_xor(ss, off);
            }
            float mu  = sum * (1.f / 256.f);
            float var = ss * (1.f / 256.f) - mu * mu;
            float rs  = rsqrtf(var + EPS);
            half4 o;
            o[0] = (_Float16)((v.x - mu) * rs * gw.x + gb.x);
            o[1] = (_Float16)((v.y - mu) * rs * gw.y + gb.y);
            o[2] = (_Float16)((v.z - mu) * rs * gw.z + gb.z);
            o[3] = (_Float16)((v.w - mu) * rs * gw.w + gb.w);
            int rl = (cc << 3) + w;
            *(half4*)(xln + rl * 264 + lane * 4) = o;

            if (c + 2 < 16) {
                int nb3 = rb + 2; if (nb3 >= 3) nb3 -= 3;
                load16_to_lds(src_of(c + 2) + lane * 4, xraw + (nb3 * 8 + w) * 256 + lane * 4);
            }
            ++rb; if (rb == 3) rb = 0;
        }
        asm volatile("s_waitcnt lgkmcnt(0)" ::: "memory");
        __builtin_amdgcn_s_barrier();

        f32x4 acc2[2] = {};
        #pragma unroll
        for (int kk = 0; kk < 8; ++kk) {
            half8 af = *(const half8*)(xln + (mt * 16 + l15) * 264 + kk * 32 + quad * 8);
            #pragma unroll
            for (int t = 0; t < 2; ++t) {
                half8 bf = *(const half8*)(WabH + (ntg * 32 + t * 16 + l15) * 256 + kk * 32 + quad * 8);
                acc2[t] = __builtin_amdgcn_mfma_f32_16x16x32_f16(af, bf, acc2[t], 0, 0, 0);
            }
        }

        #pragma unroll
        for (int t = 0; t < 2; ++t) {
            int c64  = ntg * 32 + t * 16 + l15;
            int base = ((c64 >= 32) ? 128 : 0) + (c64 & 31);
            int s_l  = half * 16 + mt * 4 + quad;
            #pragma unroll
            for (int r = 0; r < 4; ++r)
                oT[(base + r * 32) * 40 + s_l] = (_Float16)acc2[t][r];
        }
        asm volatile("s_waitcnt lgkmcnt(0)" ::: "memory");
        __builtin_amdgcn_s_barrier();
    }

    #pragma unroll
    for (int it2 = 0; it2 < 2; ++it2) {
        int u   = it2 * 512 + tid;
        int row = u >> 2;
        int off = (u & 3) * 8;
        half8 v = *(const half8*)(oT + row * 40 + off);
        _Float16* dst = (row < 128) ? aT : bT;
        int grow = i0 * 32 + (row & 127);
        *(half8*)(dst + (size_t)(sc >> 1) * AB_CHUNK + (size_t)grow * 72 + (sc & 1) * 32 + off) = v;
    }
}

// ---------------- Kernel 2: fused outer-product-mean + Wo projection ----------------
// R10: back to the proven R5 structure (512 thr, 8i x 4j, 2 blocks/CU, grid 128x64).
// ONLY phase 2 changed: 32x32x16 MFMA with split-K. Wave w -> cz quadrant (w&3, 32 cols),
// K half (w>>2, 512). M = all 32 pairs. Per MFMA step: 1 ds_read_b128 (A from oL) +
// 1 global b128 (B from WoH) -> P2 LDS reads halve (512->256/block) and P2 MFMA
// instruction count halves at identical MFMA cycles. One global stream/iter (R2 rule).
__global__ __launch_bounds__(512, 4)
void k2_main(const _Float16* __restrict__ aT, const _Float16* __restrict__ bT,
             const _Float16* __restrict__ WoH, const float* __restrict__ bo,
             float* __restrict__ out)
{
    __shared__ _Float16 smem[33024];               // 66048 B
    _Float16* sA = smem;                           // 256 rows x 72
    _Float16* sB = smem + 256 * AB_STRIDE;         // 128 rows x 72
    _Float16* oL = smem;                           // 32 pairs x 1032 (overlaps after phase 1)

    const int tid  = threadIdx.x;
    const int lane = tid & 63;
    const int w    = tid >> 6;
    const int quad = lane >> 4;
    const int l15  = lane & 15;
    const int wy   = w >> 1, wx = w & 1;

    const int jt = blockIdx.x, it = blockIdx.y;
    const char* gA = (const char*)(aT + (size_t)it * 256 * AB_STRIDE);
    const char* gB = (const char*)(bT + (size_t)jt * 128 * AB_STRIDE);

    f32x4 acc[4][4] = {};

    for (int ck = 0; ck < 2; ++ck) {
        // stage: sA 36 segs + sB 18 segs of 1024 B
        const char* cA = gA + (size_t)ck * (AB_CHUNK * 2);
        const char* cB = gB + (size_t)ck * (AB_CHUNK * 2);
        for (int seg = w; seg < 54; seg += 8) {
            if (seg < 36) load16_to_lds(cA + seg * 1024 + lane * 16, (char*)sA + seg * 1024 + lane * 16);
            else          load16_to_lds(cB + (seg - 36) * 1024 + lane * 16, (char*)sB + (seg - 36) * 1024 + lane * 16);
        }
        __syncthreads();

        #pragma unroll
        for (int kloc = 0; kloc < 2; ++kloc) {
            half8 af[4], bf[4];
            #pragma unroll
            for (int mt = 0; mt < 4; ++mt)
                af[mt] = *(const half8*)(sA + (wy * 64 + mt * 16 + l15) * AB_STRIDE + kloc * 32 + quad * 8);
            #pragma unroll
            for (int nt = 0; nt < 4; ++nt)
                bf[nt] = *(const half8*)(sB + (wx * 64 + nt * 16 + l15) * AB_STRIDE + kloc * 32 + quad * 8);
            #pragma unroll
            for (int mt = 0; mt < 4; ++mt)
                #pragma unroll
                for (int nt = 0; nt < 4; ++nt)
                    acc[mt][nt] = __builtin_amdgcn_mfma_f32_16x16x32_f16(af[mt], bf[nt], acc[mt][nt], 0, 0, 0);
        }
        __syncthreads();
    }

    // C/D -> A-operand transform into oL[pair][k'=d*32+c], XOR-swizzled 16B chunks.
    // m = wy*64+mt*16+quad*4+r: il = wy*2+(mt>>1), c = (mt&1)*16+quad*4+r
    // n = wx*64+nt*16+l15:      jl = wx*2+(nt>>1), d = (nt&1)*16+l15
    #pragma unroll
    for (int mt = 0; mt < 4; ++mt) {
        int c0     = (mt & 1) * 16 + quad * 4;
        int chunk3 = (c0 >> 3);                    // (mt&1)*2 + (quad>>1)
        int il     = wy * 2 + (mt >> 1);
        #pragma unroll
        for (int nt = 0; nt < 4; ++nt) {
            int d    = (nt & 1) * 16 + l15;
            int jl   = wx * 2 + (nt >> 1);
            int pair = il * 4 + jl;
            int cS   = (c0 & 7) + ((chunk3 ^ ((d >> 1) & 3)) << 3);   // swizzled c
            half4 v;
            v[0] = (_Float16)(acc[mt][nt][0] * (1.f / 128.f));
            v[1] = (_Float16)(acc[mt][nt][1] * (1.f / 128.f));
            v[2] = (_Float16)(acc[mt][nt][2] * (1.f / 128.f));
            v[3] = (_Float16)(acc[mt][nt][3] * (1.f / 128.f));
            *(half4*)(oL + pair * 1032 + d * 32 + cS) = v;
        }
    }
    __syncthreads();

    // Phase 2 (32x32x16, split-K): wave w -> nq = w&3 (cz quadrant), kh = w>>2 (K half).
    // A operand: lane l holds oL[pair = l&31][k' = ks*16 + (l>>5)*8 + j]; with q = ks*2 + (l>>5),
    // the stored swizzle gives byte-chunk ((q&3) ^ ((q>>3)&3)) within d-row q>>2.
    // B operand: lane l holds WoH[cz = nq*32 + (l&31)][k' = q*8 + j] (contiguous, b128).
    f32x16 zacc = {};
    const int nq = w & 3, kh = w >> 2;
    const int hi = lane >> 5;
    const int p32 = lane & 31;
    const _Float16* woB = WoH + (size_t)(nq * 32 + p32) * 1024;
    const _Float16* oaB = oL + p32 * 1032;
    const int qb = kh * 64 + hi;
    #pragma unroll 4
    for (int s = 0; s < 32; ++s) {
        int q   = qb + s * 2;
        int ach = (q & 3) ^ ((q >> 3) & 3);
        half8 oa = *(const half8*)(oaB + (q >> 2) * 32 + ach * 8);
        half8 wb = *(const half8*)(woB + q * 8);
        zacc = __builtin_amdgcn_mfma_f32_32x32x16_f16(oa, wb, zacc, 0, 0, 0);
    }
    __syncthreads();                               // all oL reads done; oL region reusable

    // split-K reduction via LDS (stride 20 floats = 80 B: conflict-free, 16B-aligned)
    float* red = (float*)smem;
    if (kh == 1) {
        float* dst = red + (nq * 64 + lane) * 20;
        #pragma unroll
        for (int r4 = 0; r4 < 4; ++r4)
            *(f32x4*)(dst + r4 * 4) = ((f32x4*)&zacc)[r4];
    }
    __syncthreads();
    if (kh == 0) {
        const float* srcr = red + (nq * 64 + lane) * 20;
        float bias = bo[nq * 32 + p32];
        #pragma unroll
        for (int r = 0; r < 16; ++r) {
            int pair = (r & 3) + 8 * (r >> 2) + 4 * hi;   // C/D row mapping (32x32)
            int il = pair >> 2, jl = pair & 3;
            out[(((size_t)(it * 8 + il)) * 512 + jt * 4 + jl) * 128 + nq * 32 + p32]
                = zacc[r] + srcr[r] + bias;
        }
    }
}

extern "C" void kernel_launch(void* const* d_in, const int* in_sizes, int n_in,
                              void* d_out, int out_size, void* d_ws, size_t ws_size,
                              hipStream_t stream)
{
    const float* x      = (const float*)d_in[0];
    const float* norm_w = (const float*)d_in[1];
    const float* norm_b = (const float*)d_in[2];
    const float* Wa     = (const float*)d_in[3];
    const float* Wb     = (const float*)d_in[4];
    const float* Wo     = (const float*)d_in[5];
    const float* bo     = (const float*)d_in[6];
    float* out = (float*)d_out;

    _Float16* aT   = (_Float16*)d_ws;                      // 2*16384*72
    _Float16* bT   = aT + 2 * (size_t)AB_CHUNK;
    _Float16* WoH  = bT + 2 * (size_t)AB_CHUNK;            // 131072
    _Float16* WabH = WoH + 131072;                         // 16384

    k_cvt<<<144, 256, 0, stream>>>(Wo, Wa, Wb, WoH, WabH);
    k1_ln_proj<<<512, 512, 0, stream>>>(x, norm_w, norm_b, WabH, aT, bT);
    k2_main<<<dim3(128, 64), 512, 0, stream>>>(aT, bT, WoH, bo, out);
}

// Round 12
// 476.413 us; speedup vs baseline: 1.0742x; 1.0021x over previous
//
#include <hip/hip_runtime.h>

// Shapes: S=128, I=J=512, CM=256, C=D=32, CZ=128. Output [1,512,512,128] fp32.
#define EPS 1e-5f

typedef _Float16 half8 __attribute__((ext_vector_type(8)));
typedef _Float16 half4 __attribute__((ext_vector_type(4)));
typedef float f32x4 __attribute__((ext_vector_type(4)));
typedef float f32x16 __attribute__((ext_vector_type(16)));

// a/b workspace layout: [2 k-chunks][16384 (i*32+c) rows][72 halves]; cols 0..63 = s_loc, 64..71 pad.
#define AB_STRIDE 72
#define AB_CHUNK  (16384 * AB_STRIDE)

__device__ __forceinline__ void load16_to_lds(const void* g, void* l) {
    __builtin_amdgcn_global_load_lds((__attribute__((address_space(1))) void*)g,
                                     (__attribute__((address_space(3))) void*)l, 16, 0, 0);
}

// ---------------- cvt kernel: WoH (fp16, K permuted to k'=d*32+c) + WabH (fp16) ----------------
__global__ __launch_bounds__(256)
void k_cvt(const float* __restrict__ Wo, const float* __restrict__ Wa,
           const float* __restrict__ Wb, _Float16* __restrict__ WoH,
           _Float16* __restrict__ WabH)
{
    __shared__ _Float16 tile[32 * 36];          // [d][c], pad 36 keeps half4 reads 8B-aligned
    const int t = threadIdx.x;
    if (blockIdx.x < 128) {
        const int n = blockIdx.x;
        float4 v = *(const float4*)(Wo + (size_t)n * 1024 + t * 4);
        int c  = t >> 3;
        int d0 = (t * 4) & 31;
        tile[(d0 + 0) * 36 + c] = (_Float16)v.x;
        tile[(d0 + 1) * 36 + c] = (_Float16)v.y;
        tile[(d0 + 2) * 36 + c] = (_Float16)v.z;
        tile[(d0 + 3) * 36 + c] = (_Float16)v.w;
        __syncthreads();
        int d  = t >> 3;
        int c0 = (t * 4) & 31;
        half4 o = *(const half4*)(tile + d * 36 + c0);
        *(half4*)(WoH + (size_t)n * 1024 + t * 4) = o;
    } else {
        int idx = ((blockIdx.x - 128) * 256 + t) * 4;
        const float* src = (idx < 8192) ? (Wa + idx) : (Wb + (idx - 8192));
        float4 v = *(const float4*)src;
        half4 h;
        h[0] = (_Float16)v.x; h[1] = (_Float16)v.y; h[2] = (_Float16)v.z; h[3] = (_Float16)v.w;
        *(half4*)(WabH + idx) = h;
    }
}

// ---------------- Kernel 1: LN + A/B projection, DMA-pipelined x staging ----------------
// (unchanged — measured neutral vs scalar variants; k1 is not the bottleneck)
__global__ __launch_bounds__(512, 4)
void k1_ln_proj(const float* __restrict__ x, const float* __restrict__ nw,
                const float* __restrict__ nb, const _Float16* __restrict__ WabH,
                _Float16* __restrict__ aT, _Float16* __restrict__ bT)
{
    __shared__ float    xraw[3 * 8 * 256];   // 24576 B
    __shared__ _Float16 xln[64 * 264];       // 33792 B
    __shared__ _Float16 oT[256 * 40];        // 20480 B

    const int tid  = threadIdx.x;
    const int lane = tid & 63;
    const int w    = tid >> 6;
    const int quad = lane >> 4;
    const int l15  = lane & 15;
    const int i0   = (blockIdx.x >> 2) * 4;
    const int sc   = blockIdx.x & 3;

    const int mt  = w & 3;
    const int ntg = w >> 2;

    const float4 gw = ((const float4*)nw)[lane];
    const float4 gb = ((const float4*)nb)[lane];

    auto src_of = [&](int c) -> const float* {
        int rl = ((c & 7) << 3) + w;
        int s_ = sc * 32 + ((c >> 3) << 4) + (rl >> 2);
        int i_ = i0 + (rl & 3);
        return x + ((size_t)s_ * 512 + i_) * 256;
    };

    load16_to_lds(src_of(0) + lane * 4, xraw + (0 * 8 + w) * 256 + lane * 4);
    load16_to_lds(src_of(1) + lane * 4, xraw + (1 * 8 + w) * 256 + lane * 4);

    int rb = 0;
    for (int half = 0; half < 2; ++half) {
        for (int cc = 0; cc < 8; ++cc) {
            const int c = half * 8 + cc;
            if (c == 15) asm volatile("s_waitcnt vmcnt(0)" ::: "memory");
            else         asm volatile("s_waitcnt vmcnt(1)" ::: "memory");

            const float4 v = *(const float4*)(xraw + (rb * 8 + w) * 256 + lane * 4);
            float sum = v.x + v.y + v.z + v.w;
            float ss  = v.x * v.x + v.y * v.y + v.z * v.z + v.w * v.w;
            #pragma unroll
            for (int off = 32; off > 0; off >>= 1) {
                sum += __shfl_xor(sum, off);
                ss  += __shfl_xor(ss, off);
            }
            float mu  = sum * (1.f / 256.f);
            float var = ss * (1.f / 256.f) - mu * mu;
            float rs  = rsqrtf(var + EPS);
            half4 o;
            o[0] = (_Float16)((v.x - mu) * rs * gw.x + gb.x);
            o[1] = (_Float16)((v.y - mu) * rs * gw.y + gb.y);
            o[2] = (_Float16)((v.z - mu) * rs * gw.z + gb.z);
            o[3] = (_Float16)((v.w - mu) * rs * gw.w + gb.w);
            int rl = (cc << 3) + w;
            *(half4*)(xln + rl * 264 + lane * 4) = o;

            if (c + 2 < 16) {
                int nb3 = rb + 2; if (nb3 >= 3) nb3 -= 3;
                load16_to_lds(src_of(c + 2) + lane * 4, xraw + (nb3 * 8 + w) * 256 + lane * 4);
            }
            ++rb; if (rb == 3) rb = 0;
        }
        asm volatile("s_waitcnt lgkmcnt(0)" ::: "memory");
        __builtin_amdgcn_s_barrier();

        f32x4 acc2[2] = {};
        #pragma unroll
        for (int kk = 0; kk < 8; ++kk) {
            half8 af = *(const half8*)(xln + (mt * 16 + l15) * 264 + kk * 32 + quad * 8);
            #pragma unroll
            for (int t = 0; t < 2; ++t) {
                half8 bf = *(const half8*)(WabH + (ntg * 32 + t * 16 + l15) * 256 + kk * 32 + quad * 8);
                acc2[t] = __builtin_amdgcn_mfma_f32_16x16x32_f16(af, bf, acc2[t], 0, 0, 0);
            }
        }

        #pragma unroll
        for (int t = 0; t < 2; ++t) {
            int c64  = ntg * 32 + t * 16 + l15;
            int base = ((c64 >= 32) ? 128 : 0) + (c64 & 31);
            int s_l  = half * 16 + mt * 4 + quad;
            #pragma unroll
            for (int r = 0; r < 4; ++r)
                oT[(base + r * 32) * 40 + s_l] = (_Float16)acc2[t][r];
        }
        asm volatile("s_waitcnt lgkmcnt(0)" ::: "memory");
        __builtin_amdgcn_s_barrier();
    }

    #pragma unroll
    for (int it2 = 0; it2 < 2; ++it2) {
        int u   = it2 * 512 + tid;
        int row = u >> 2;
        int off = (u & 3) * 8;
        half8 v = *(const half8*)(oT + row * 40 + off);
        _Float16* dst = (row < 128) ? aT : bT;
        int grow = i0 * 32 + (row & 127);
        *(half8*)(dst + (size_t)(sc >> 1) * AB_CHUNK + (size_t)grow * 72 + (sc & 1) * 32 + off) = v;
    }
}

// ---------------- Kernel 2: fused outer-product-mean + Wo projection ----------------
// R11: R10 body unchanged; ONLY change is XCD-aware bijective block swizzle (T1).
// 1D grid 8192; HW round-robins consecutive blockIdx across the 8 XCDs, so xcd = wid&7
// owns a contiguous 32it x 32jt tile: per-XCD L2 working set = A 2.4MB + B 1.2MB +
// WoH 0.26MB ~= 3.8MB -> L2-resident (vs ~9.4MB random before). Targets the aT/bT
// staging path (900 MB/dispatch re-read, previously L3-served with exposed vmcnt(0)
// drain at the staging barrier).
__global__ __launch_bounds__(512, 4)
void k2_main(const _Float16* __restrict__ aT, const _Float16* __restrict__ bT,
             const _Float16* __restrict__ WoH, const float* __restrict__ bo,
             float* __restrict__ out)
{
    __shared__ _Float16 smem[33024];               // 66048 B
    _Float16* sA = smem;                           // 256 rows x 72
    _Float16* sB = smem + 256 * AB_STRIDE;         // 128 rows x 72
    _Float16* oL = smem;                           // 32 pairs x 1032 (overlaps after phase 1)

    const int tid  = threadIdx.x;
    const int lane = tid & 63;
    const int w    = tid >> 6;
    const int quad = lane >> 4;
    const int l15  = lane & 15;
    const int wy   = w >> 1, wx = w & 1;

    // XCD-aware swizzle: xcd (wid&7) -> tile (it in [ (xcd>>2)*32, +32 ), jt in [ (xcd&3)*32, +32 ))
    const int wid = blockIdx.x;
    const int xcd = wid & 7;
    const int loc = wid >> 3;                      // 0..1023
    const int it  = (xcd >> 2) * 32 + (loc >> 5);
    const int jt  = (xcd & 3) * 32 + (loc & 31);

    const char* gA = (const char*)(aT + (size_t)it * 256 * AB_STRIDE);
    const char* gB = (const char*)(bT + (size_t)jt * 128 * AB_STRIDE);

    f32x4 acc[4][4] = {};

    for (int ck = 0; ck < 2; ++ck) {
        // stage: sA 36 segs + sB 18 segs of 1024 B
        const char* cA = gA + (size_t)ck * (AB_CHUNK * 2);
        const char* cB = gB + (size_t)ck * (AB_CHUNK * 2);
        for (int seg = w; seg < 54; seg += 8) {
            if (seg < 36) load16_to_lds(cA + seg * 1024 + lane * 16, (char*)sA + seg * 1024 + lane * 16);
            else          load16_to_lds(cB + (seg - 36) * 1024 + lane * 16, (char*)sB + (seg - 36) * 1024 + lane * 16);
        }
        __syncthreads();

        #pragma unroll
        for (int kloc = 0; kloc < 2; ++kloc) {
            half8 af[4], bf[4];
            #pragma unroll
            for (int mt = 0; mt < 4; ++mt)
                af[mt] = *(const half8*)(sA + (wy * 64 + mt * 16 + l15) * AB_STRIDE + kloc * 32 + quad * 8);
            #pragma unroll
            for (int nt = 0; nt < 4; ++nt)
                bf[nt] = *(const half8*)(sB + (wx * 64 + nt * 16 + l15) * AB_STRIDE + kloc * 32 + quad * 8);
            #pragma unroll
            for (int mt = 0; mt < 4; ++mt)
                #pragma unroll
                for (int nt = 0; nt < 4; ++nt)
                    acc[mt][nt] = __builtin_amdgcn_mfma_f32_16x16x32_f16(af[mt], bf[nt], acc[mt][nt], 0, 0, 0);
        }
        __syncthreads();
    }

    // C/D -> A-operand transform into oL[pair][k'=d*32+c], XOR-swizzled 16B chunks.
    // m = wy*64+mt*16+quad*4+r: il = wy*2+(mt>>1), c = (mt&1)*16+quad*4+r
    // n = wx*64+nt*16+l15:      jl = wx*2+(nt>>1), d = (nt&1)*16+l15
    #pragma unroll
    for (int mt = 0; mt < 4; ++mt) {
        int c0     = (mt & 1) * 16 + quad * 4;
        int chunk3 = (c0 >> 3);                    // (mt&1)*2 + (quad>>1)
        int il     = wy * 2 + (mt >> 1);
        #pragma unroll
        for (int nt = 0; nt < 4; ++nt) {
            int d    = (nt & 1) * 16 + l15;
            int jl   = wx * 2 + (nt >> 1);
            int pair = il * 4 + jl;
            int cS   = (c0 & 7) + ((chunk3 ^ ((d >> 1) & 3)) << 3);   // swizzled c
            half4 v;
            v[0] = (_Float16)(acc[mt][nt][0] * (1.f / 128.f));
            v[1] = (_Float16)(acc[mt][nt][1] * (1.f / 128.f));
            v[2] = (_Float16)(acc[mt][nt][2] * (1.f / 128.f));
            v[3] = (_Float16)(acc[mt][nt][3] * (1.f / 128.f));
            *(half4*)(oL + pair * 1032 + d * 32 + cS) = v;
        }
    }
    __syncthreads();

    // Phase 2 (32x32x16, split-K): wave w -> nq = w&3 (cz quadrant), kh = w>>2 (K half).
    // A operand: lane l holds oL[pair = l&31][k' = ks*16 + (l>>5)*8 + j]; with q = ks*2 + (l>>5),
    // the stored swizzle gives byte-chunk ((q&3) ^ ((q>>3)&3)) within d-row q>>2.
    // B operand: lane l holds WoH[cz = nq*32 + (l&31)][k' = q*8 + j] (contiguous, b128).
    f32x16 zacc = {};
    const int nq = w & 3, kh = w >> 2;
    const int hi = lane >> 5;
    const int p32 = lane & 31;
    const _Float16* woB = WoH + (size_t)(nq * 32 + p32) * 1024;
    const _Float16* oaB = oL + p32 * 1032;
    const int qb = kh * 64 + hi;
    #pragma unroll 4
    for (int s = 0; s < 32; ++s) {
        int q   = qb + s * 2;
        int ach = (q & 3) ^ ((q >> 3) & 3);
        half8 oa = *(const half8*)(oaB + (q >> 2) * 32 + ach * 8);
        half8 wb = *(const half8*)(woB + q * 8);
        zacc = __builtin_amdgcn_mfma_f32_32x32x16_f16(oa, wb, zacc, 0, 0, 0);
    }
    __syncthreads();                               // all oL reads done; oL region reusable

    // split-K reduction via LDS (stride 20 floats = 80 B: conflict-free, 16B-aligned)
    float* red = (float*)smem;
    if (kh == 1) {
        float* dst = red + (nq * 64 + lane) * 20;
        #pragma unroll
        for (int r4 = 0; r4 < 4; ++r4)
            *(f32x4*)(dst + r4 * 4) = ((f32x4*)&zacc)[r4];
    }
    __syncthreads();
    if (kh == 0) {
        const float* srcr = red + (nq * 64 + lane) * 20;
        float bias = bo[nq * 32 + p32];
        #pragma unroll
        for (int r = 0; r < 16; ++r) {
            int pair = (r & 3) + 8 * (r >> 2) + 4 * hi;   // C/D row mapping (32x32)
            int il = pair >> 2, jl = pair & 3;
            out[(((size_t)(it * 8 + il)) * 512 + jt * 4 + jl) * 128 + nq * 32 + p32]
                = zacc[r] + srcr[r] + bias;
        }
    }
}

extern "C" void kernel_launch(void* const* d_in, const int* in_sizes, int n_in,
                              void* d_out, int out_size, void* d_ws, size_t ws_size,
                              hipStream_t stream)
{
    const float* x      = (const float*)d_in[0];
    const float* norm_w = (const float*)d_in[1];
    const float* norm_b = (const float*)d_in[2];
    const float* Wa     = (const float*)d_in[3];
    const float* Wb     = (const float*)d_in[4];
    const float* Wo     = (const float*)d_in[5];
    const float* bo     = (const float*)d_in[6];
    float* out = (float*)d_out;

    _Float16* aT   = (_Float16*)d_ws;                      // 2*16384*72
    _Float16* bT   = aT + 2 * (size_t)AB_CHUNK;
    _Float16* WoH  = bT + 2 * (size_t)AB_CHUNK;            // 131072
    _Float16* WabH = WoH + 131072;                         // 16384

    k_cvt<<<144, 256, 0, stream>>>(Wo, Wa, Wb, WoH, WabH);
    k1_ln_proj<<<512, 512, 0, stream>>>(x, norm_w, norm_b, WabH, aT, bT);
    k2_main<<<8192, 512, 0, stream>>>(aT, bT, WoH, bo, out);
}